// Round 13
// baseline (198.413 us; speedup 1.0000x reference)
//
#include <hip/hip_runtime.h>
#include <math.h>

#define N_ROWS 16384
#define DIM 4096
#define NEXP 64
#define RPB 32
#define NCH 64                  // 32-k chunks per k-half (2048/32)
#define NSTEP (DIM / 16)        // 256 global K-steps of 16

typedef short short8 __attribute__((ext_vector_type(8)));
typedef float f32x16 __attribute__((ext_vector_type(16)));

__device__ __forceinline__ unsigned cvt_pk_bf16(float a, float b) {
    unsigned r;
    asm("v_cvt_pk_bf16_f32 %0, %1, %2" : "=v"(r) : "v"(a), "v"(b));
    return r;   // low16 = bf16(a), high16 = bf16(b)
}

// 3-way split of 8 f32 into bf16 hi/mid/lo frags; residuals exact (<= 2^-27 |x|).
__device__ __forceinline__ void split3(const float* xv, short8& h8, short8& m8, short8& l8) {
    union { unsigned u[4]; short8 s; } H, M, L;
#pragma unroll
    for (int j = 0; j < 4; ++j) {
        float a = xv[2 * j], b = xv[2 * j + 1];
        unsigned hp = cvt_pk_bf16(a, b);
        float a1 = a - __uint_as_float(hp << 16);
        float b1 = b - __uint_as_float(hp & 0xffff0000u);
        unsigned mp = cvt_pk_bf16(a1, b1);
        float a2 = a1 - __uint_as_float(mp << 16);
        float b2 = b1 - __uint_as_float(mp & 0xffff0000u);
        H.u[j] = hp; M.u[j] = mp; L.u[j] = cvt_pk_bf16(a2, b2);
    }
    h8 = H.s; m8 = M.s; l8 = L.s;
}

__device__ __forceinline__ bool gtpair(float a, int ia, float b, int ib) {
    return (a > b) || (a == b && ia < ib);
}

// ---- pre-kernel (r9-verified): W -> 3 bf16 tables, idx = (s*2+nt)*64+l,
// e = nt*32 + (l&31), k = s*16 + (l>>5)*8 (32x32 B-frag lane mapping) ----
__global__ __launch_bounds__(256)
void convw_kernel(const float* __restrict__ w, short8* __restrict__ w0t,
                  short8* __restrict__ w1t, short8* __restrict__ w2t)
{
    const int t  = blockIdx.x * 256 + threadIdx.x;   // 32768 = 256 s x 2 nt x 64 l
    const int s  = t >> 7;
    const int nt = (t >> 6) & 1;
    const int l  = t & 63;
    const int e  = nt * 32 + (l & 31);
    const int k  = s * 16 + (l >> 5) * 8;
    const float* src = w + (size_t)e * DIM + k;
    float xv[8];
#pragma unroll
    for (int j = 0; j < 8; ++j) xv[j] = src[j];
    short8 h, m, lo;
    split3(xv, h, m, lo);
    w0t[t] = h; w1t[t] = m; w2t[t] = lo;
}

__device__ __forceinline__ void load16s(const short8* g, short8* l) {
    __builtin_amdgcn_global_load_lds(
        (const __attribute__((address_space(1))) void*)g,
        (__attribute__((address_space(3))) void*)l, 16, 0, 0);
}

#define MFMA32(A, B, C) __builtin_amdgcn_mfma_f32_32x32x16_bf16((A), (B), (C), 0, 0, 0)

// ---- main: 512 blocks x 4 waves = (kh, nh). Wave: all 32 rows x 32 experts
// (nh half) x k-half 2048 (64 chunks of 32). W-frag rows (S*2+nh) are
// nh-DISJOINT -> wave-private LDS double-buffer, NO barriers in main loop.
// Pipeline: counted vmcnt(10) drains the 2-bodies-ago group (6 stages + 4 x
// loads per body, robust to intra-body reorder); lgkmcnt(0) frees the buffer
// before re-staging (WAR is same-wave only). x: plain 2-deep register
// prefetch, compiler-managed waits. C (m74/m101, r9-verified):
// col = lane&31, row = (reg&3) + 8*(reg>>2) + 4*(lane>>5).
__global__ __launch_bounds__(256, 2)
void gate_kernel(const float* __restrict__ x, const short8* __restrict__ w0t,
                 const short8* __restrict__ w1t, const short8* __restrict__ w2t,
                 float* __restrict__ out)
{
    __shared__ short8 wstg[4][2][6][64];    // [wave][buf][frag=tbl*2+s][lane] = 48KB

    const int tid  = threadIdx.x;
    const int lane = tid & 63;
    const int wv   = tid >> 6;
    const int kh   = wv >> 1;
    const int nh   = wv & 1;
    const int e31  = lane & 31;
    const int hf   = lane >> 5;
    const int row0 = blockIdx.x * RPB;

    f32x16 acc;
#pragma unroll
    for (int j = 0; j < 16; ++j) acc[j] = 0.f;

    const float* xq = x + (size_t)(row0 + e31) * DIM + kh * 2048 + hf * 8;

#define STAGE6(C, B)                                                           \
    do {                                                                       \
        _Pragma("unroll")                                                      \
        for (int fs_ = 0; fs_ < 6; ++fs_) {                                    \
            const int tbl_ = fs_ >> 1, s_ = fs_ & 1;                           \
            const int S_ = kh * 128 + (C) * 2 + s_;                            \
            const short8* tb_ = (tbl_ == 0) ? w0t : (tbl_ == 1) ? w1t : w2t;   \
            load16s(tb_ + (size_t)(S_ * 2 + nh) * 64 + lane,                   \
                    &wstg[wv][B][fs_][0]);                                     \
        }                                                                      \
    } while (0)

#define XLD(V0, V1, V2, V3, C)                                                 \
    do {                                                                       \
        V0 = *reinterpret_cast<const float4*>(xq + (C) * 32);                  \
        V1 = *reinterpret_cast<const float4*>(xq + (C) * 32 + 4);              \
        V2 = *reinterpret_cast<const float4*>(xq + (C) * 32 + 16);             \
        V3 = *reinterpret_cast<const float4*>(xq + (C) * 32 + 20);             \
    } while (0)

#define BODY(T, X0, X1, X2, X3)                                                \
    do {                                                                       \
        asm volatile("s_waitcnt vmcnt(10)" ::: "memory");                      \
        const int tc_ = ((T) + 2 > NCH - 1) ? NCH - 1 : (T) + 2;               \
        short8 f00 = wstg[wv][(T) & 1][0][lane];                               \
        short8 f01 = wstg[wv][(T) & 1][1][lane];                               \
        short8 f10 = wstg[wv][(T) & 1][2][lane];                               \
        short8 f11 = wstg[wv][(T) & 1][3][lane];                               \
        short8 f20 = wstg[wv][(T) & 1][4][lane];                               \
        short8 f21 = wstg[wv][(T) & 1][5][lane];                               \
        asm volatile("s_waitcnt lgkmcnt(0)" ::: "memory");                     \
        STAGE6(tc_, (T) & 1);                                                  \
        float v0_[8] = {X0.x, X0.y, X0.z, X0.w, X1.x, X1.y, X1.z, X1.w};       \
        float v1_[8] = {X2.x, X2.y, X2.z, X2.w, X3.x, X3.y, X3.z, X3.w};       \
        short8 a0h, a0m, a0l, a1h, a1m, a1l;                                   \
        split3(v0_, a0h, a0m, a0l);                                            \
        split3(v1_, a1h, a1m, a1l);                                            \
        XLD(X0, X1, X2, X3, tc_);                                              \
        acc = MFMA32(a0l, f00, acc);                                           \
        acc = MFMA32(a0m, f10, acc);                                           \
        acc = MFMA32(a0h, f20, acc);                                           \
        acc = MFMA32(a0m, f00, acc);                                           \
        acc = MFMA32(a0h, f10, acc);                                           \
        acc = MFMA32(a0h, f00, acc);                                           \
        acc = MFMA32(a1l, f01, acc);                                           \
        acc = MFMA32(a1m, f11, acc);                                           \
        acc = MFMA32(a1h, f21, acc);                                           \
        acc = MFMA32(a1m, f01, acc);                                           \
        acc = MFMA32(a1h, f11, acc);                                           \
        acc = MFMA32(a1h, f01, acc);                                           \
    } while (0)

    // prologue: group order [chunk0(6W+4x)] [chunk1(6W+4x)] pinned by fence
    float4 xA0, xA1, xA2, xA3, xB0, xB1, xB2, xB3;
    STAGE6(0, 0);
    XLD(xA0, xA1, xA2, xA3, 0);
    asm volatile("" ::: "memory");
    STAGE6(1, 1);
    XLD(xB0, xB1, xB2, xB3, 1);

    for (int t = 0; t < NCH; t += 2) {
        BODY(t,     xA0, xA1, xA2, xA3);
        BODY(t + 1, xB0, xB1, xB2, xB3);
    }

    asm volatile("s_waitcnt vmcnt(0)" ::: "memory");
    __syncthreads();

    // ---- k-half partials exchange: pf[kh*32 + row][64 experts] (reuse wstg) ----
    float* pf = (float*)&wstg[0][0][0][0];
#pragma unroll
    for (int reg = 0; reg < 16; ++reg) {
        const int rw = (reg & 3) + 8 * (reg >> 2) + 4 * hf;
        pf[(kh * 32 + rw) * 64 + nh * 32 + e31] = acc[reg];
    }
    __syncthreads();

    float* out_vals = out;                          // [N][2]
    float* out_idx  = out + (size_t)N_ROWS * 2;     // [N][2] (as float)
    float* out_sc   = out + (size_t)N_ROWS * 4;     // [N][64]

    // wave wv finalizes rows wv*8 .. wv*8+7; lane = expert
#pragma unroll
    for (int i = 0; i < 8; ++i) {
        const int r = wv * 8 + i;
        const int row = row0 + r;
        float s = pf[r * 64 + lane] + pf[(32 + r) * 64 + lane];
        float m = s;
#pragma unroll
        for (int off = 32; off; off >>= 1) m = fmaxf(m, __shfl_xor(m, off));
        float e = expf(s - m);
        float sum = e;
#pragma unroll
        for (int off = 32; off; off >>= 1) sum += __shfl_xor(sum, off);
        float p = e / sum;
        out_sc[(size_t)row * 64 + lane] = p;

        // top-2 butterfly over 64 lanes (tie -> lowest index, matches lax.top_k)
        float v1 = p; int i1 = lane; float v2 = -1.f; int i2 = lane;
#pragma unroll
        for (int off = 32; off; off >>= 1) {
            float o1 = __shfl_xor(v1, off); int oi1 = __shfl_xor(i1, off);
            float o2 = __shfl_xor(v2, off); int oi2 = __shfl_xor(i2, off);
            if (gtpair(o1, oi1, v1, i1)) {
                if (gtpair(v1, i1, o2, oi2)) { v2 = v1; i2 = i1; }
                else                         { v2 = o2; i2 = oi2; }
                v1 = o1; i1 = oi1;
            } else if (gtpair(o1, oi1, v2, i2)) {
                v2 = o1; i2 = oi1;
            }
        }
        if (lane == 0) {
            out_vals[(size_t)row * 2 + 0] = v1;     // ROUTE_SCALE == 1.0
            out_vals[(size_t)row * 2 + 1] = v2;
            out_idx[(size_t)row * 2 + 0]  = (float)i1;
            out_idx[(size_t)row * 2 + 1]  = (float)i2;
        }
    }
}

extern "C" void kernel_launch(void* const* d_in, const int* in_sizes, int n_in,
                              void* d_out, int out_size, void* d_ws, size_t ws_size,
                              hipStream_t stream)
{
    const float* x = (const float*)d_in[0];
    const float* w = (const float*)d_in[1];
    float* out = (float*)d_out;

    short8* w0t = (short8*)d_ws;                    // 512 KB
    short8* w1t = w0t + (size_t)NSTEP * 2 * 64;     // 512 KB
    short8* w2t = w1t + (size_t)NSTEP * 2 * 64;     // 512 KB

    convw_kernel<<<dim3(128), dim3(256), 0, stream>>>(w, w0t, w1t, w2t);
    gate_kernel<<<dim3(N_ROWS / RPB), dim3(256), 0, stream>>>(x, w0t, w1t, w2t, out);
}